// Round 13
// baseline (30.881 us; speedup 1.0000x reference)
//
#include <hip/hip_runtime.h>
#include <float.h>
#include <math.h>

// Problem constants (fixed by reference)
#define NB    8
#define K1    2048
#define K2    8192
#define NADD  16
#define PP    128          // K1 / NUM_ADD
#define FEPS  1e-7f
#define CDW   0.1f

// Kernel P: 64 farthest blocks + 64 pack blocks
#define FAR_GRID  64
#define PACK_GRID 64
#define GRID_P    (FAR_GRID + PACK_GRID)

// Kernel A: block = (b, rowblk of 32 adv rows, ori half of 4096 pts)
// 1024 blocks x 32KB LDS -> 4 blocks/CU resident = 16 waves/CU = 4/SIMD
#define CH_GRID   (NB * 64 * 2)     // 1024

// Kernel B: 64 reduce blocks + last-done combine
#define RB_GRID   64

// ws layout (float offsets)
#define PMIN_OFF  0                       // [2][NB][K1] = 32768 floats
#define FARW_OFF  32768                   // 128 floats
#define CHB_OFF   (FARW_OFF + NB * NADD)  // 64 floats
#define CTR_OFF   (CHB_OFF + 64)
#define PK_OFF    33024                   // byte 132096, 16B aligned; 64K u64

typedef __bf16 bf16x8 __attribute__((ext_vector_type(8)));
typedef float  f32x16 __attribute__((ext_vector_type(16)));
typedef unsigned long long u64;

// fp32 -> bf16 bits, round-to-nearest-even (proven R11/R12, absmax 0)
__device__ __forceinline__ u64 bfbits(float x) {
    union { float f; unsigned int u; } c; c.f = x;
    unsigned int u = c.u;
    u += 0x7fffu + ((u >> 16) & 1u);
    return (u64)(u >> 16);
}
__device__ __forceinline__ u64 pack3(float x, float y, float z) {
    float o2 = fmaf(x, x, fmaf(y, y, z * z));
    return bfbits(x) | (bfbits(y) << 16) | (bfbits(z) << 32) | (bfbits(o2) << 48);
}

// ---------------------------------------------------------------------------
// Kernel P: farthest (blocks 0..63, exact fp32) + ori pre-pack (64..127).
// Pack: ori -> pk[b][8192] as bf16x4 [x,y,z,|o|^2] (8 B/point), done ONCE.
// ---------------------------------------------------------------------------
__global__ __launch_bounds__(256) void prep_far(const float* __restrict__ adv,
                                                const float* __restrict__ ori,
                                                u64* __restrict__ pk,
                                                float* __restrict__ farw,
                                                unsigned int* __restrict__ ctr) {
    __shared__ float sf[768];
    __shared__ float sred[4];
    const int bid = blockIdx.x;
    const int t   = threadIdx.x;

    if (bid < FAR_GRID) {
        // ---- farthest: block = (b, cluster-pair), 128 threads per cluster ----
        const int b  = bid >> 3;
        const int cp = bid & 7;
        const int g  = t >> 7;
        const int p  = t & 127;
        const int ci = cp * 2 + g;

        const float* c = adv + (size_t)(b * K1 + ci * PP) * 3;
        float px = c[p * 3 + 0], py = c[p * 3 + 1], pz = c[p * 3 + 2];
        float* sx = sf + g * 384;
        sx[p] = px; sx[128 + p] = py; sx[256 + p] = pz;
        __syncthreads();

        const float pxm = px - FEPS, pym = py - FEPS, pzm = pz - FEPS;
        float mx = 0.f;
#pragma unroll 8
        for (int q = 0; q < PP; ++q) {
            float dx = sx[q] - pxm;
            float dy = sx[128 + q] - pym;
            float dz = sx[256 + q] - pzm;
            mx = fmaxf(mx, fmaf(dx, dx, fmaf(dy, dy, dz * dz)));
        }
#pragma unroll
        for (int off = 32; off; off >>= 1) mx = fmaxf(mx, __shfl_down(mx, off, 64));
        if ((t & 63) == 0) sred[t >> 6] = mx;
        __syncthreads();
        if (t == 0)   farw[b * NADD + cp * 2 + 0] = sqrtf(fmaxf(sred[0], sred[1]));
        if (t == 128) farw[b * NADD + cp * 2 + 1] = sqrtf(fmaxf(sred[2], sred[3]));
    } else {
        // ---- pack: block pb covers 1024 points (4 per thread) ----
        if (bid == FAR_GRID && t == 0) *ctr = 0u;   // reset kernel-B counter
        const int pb  = bid - FAR_GRID;
        const int b   = pb >> 3;
        const int seg = pb & 7;
        const int idx0 = seg * 1024 + t * 4;
        const float4* f4 = (const float4*)ori + ((size_t)(b * K2 + idx0) * 3) / 4;
        float4 f0 = f4[0], f1 = f4[1], f2 = f4[2];
        u64 w0 = pack3(f0.x, f0.y, f0.z);
        u64 w1 = pack3(f0.w, f1.x, f1.y);
        u64 w2 = pack3(f1.z, f1.w, f2.x);
        u64 w3 = pack3(f2.y, f2.z, f2.w);
        ulonglong2* dst = (ulonglong2*)&pk[(size_t)b * K2 + idx0];
        dst[0] = make_ulonglong2(w0, w1);
        dst[1] = make_ulonglong2(w2, w3);
    }
}

// ---------------------------------------------------------------------------
// Kernel A: MFMA chamfer partial. Block = (b, rowblk, half):
//   - copy 4096 pre-packed points (32 KB) global -> LDS (pure DMA, no VALU)
//   - each wave: 32 tiles of 32 ori pts vs the block's 32 adv rows using
//     v_mfma_f32_32x32x16_bf16: a' = (-2ax,-2ay,-2az,1)/4 quad replicated in
//     both j-quads of the lane (and both lane halves), o' likewise duplicated
//     -> acc = o^2 - 2 a.o for (row,col) under any per-group monotone K map
//     (same replication trick verified absmax=0 in R11).
//   - min over 16 acc regs per tile; butterfly over lane&31 (cols); cross-wave
//     min in LDS -> pmins[half][b][row].
// C layout (m74/m101): col = lane&31, row = (r&3) + 8*(r>>2) + 4*(lane>>5).
// ---------------------------------------------------------------------------
__global__ __launch_bounds__(256) void chamfer_a(const float* __restrict__ adv,
                                                 const u64* __restrict__ pk,
                                                 float* __restrict__ pmins) {
    __shared__ u64 so[4096];           // 32 KB
    __shared__ float smin[4][32];
    const int bid  = blockIdx.x;
    const int t    = threadIdx.x;
    const int b    = bid >> 7;
    const int rowblk = (bid >> 1) & 63;
    const int half = bid & 1;
    const int rowb = rowblk * 32;
    const int lane = t & 63;
    const int wv   = t >> 6;

    // stage packed half (pure copy, coalesced 8B/lane)
    const u64* src = pk + (size_t)b * K2 + half * 4096;
#pragma unroll
    for (int i = 0; i < 16; ++i) so[i * 256 + t] = src[i * 256 + t];

    // A fragment: row = lane&31, quad replicated in both j-quads, 1/4 scale
    const float* a0 = adv + ((size_t)b * K1 + rowb + (lane & 31)) * 3;
    u64 q = bfbits(-0.5f * a0[0]) | (bfbits(-0.5f * a0[1]) << 16)
          | (bfbits(-0.5f * a0[2]) << 32) | (0x3e80ULL << 48);  // bf16(0.25)
    const bf16x8 af = __builtin_bit_cast(bf16x8, make_ulonglong2(q, q));
    __syncthreads();

    const f32x16 z16 = {};
    f32x16 m;
#pragma unroll
    for (int r = 0; r < 16; ++r) m[r] = FLT_MAX;

#pragma unroll 4
    for (int tl = 0; tl < 32; ++tl) {
        u64 lo = so[wv * 1024 + tl * 32 + (lane & 31)];   // 2-way bcast, 2-way bank (free)
        bf16x8 bf = __builtin_bit_cast(bf16x8, make_ulonglong2(lo, lo));
        f32x16 acc = __builtin_amdgcn_mfma_f32_32x32x16_bf16(af, bf, z16, 0, 0, 0);
#pragma unroll
        for (int r = 0; r < 16; ++r) m[r] = fminf(m[r], acc[r]);
    }

    // min over 32 cols: butterfly on lane&31; rows land per C layout
#pragma unroll
    for (int r = 0; r < 16; ++r) {
        float v = m[r];
#pragma unroll
        for (int msk = 1; msk < 32; msk <<= 1) v = fminf(v, __shfl_xor(v, msk, 64));
        if ((lane & 31) == 0)
            smin[wv][(r & 3) + 8 * (r >> 2) + 4 * (lane >> 5)] = v;
    }
    __syncthreads();

    if (t < 32) {
        float mm = fminf(fminf(smin[0][t], smin[1][t]),
                         fminf(smin[2][t], smin[3][t]));
        pmins[((size_t)half * NB + b) * K1 + rowb + t] = mm;
    }
}

// ---------------------------------------------------------------------------
// Kernel B: min over 2 halves + a^2 + clamp + per-(b,kc) sum; last-done block
// does the final weighted combine (proven R9 pattern, 64 returned RMWs).
// ---------------------------------------------------------------------------
__global__ __launch_bounds__(256) void reduce_b(const float* __restrict__ adv,
                                                const float* __restrict__ pmins,
                                                const float* __restrict__ farw,
                                                const float* __restrict__ w,
                                                float* __restrict__ chbp,
                                                unsigned int* __restrict__ ctr,
                                                float* __restrict__ out) {
    __shared__ float s[4];
    __shared__ unsigned int lastflag;
    const int t  = threadIdx.x;
    const int kc = blockIdx.x & 7;
    const int b  = blockIdx.x >> 3;
    const int k  = kc * 256 + t;

    float m = fminf(pmins[(size_t)b * K1 + k],
                    pmins[((size_t)NB + b) * K1 + k]);
    const float* a = adv + ((size_t)b * K1 + k) * 3;
    float a2 = fmaf(a[0], a[0], fmaf(a[1], a[1], a[2] * a[2]));
    float sum = fmaxf(a2 + m, 0.f);          // clamp commutes with min

#pragma unroll
    for (int off = 32; off; off >>= 1) sum += __shfl_down(sum, off, 64);
    const int lane = t & 63, wid = t >> 6;
    if (lane == 0) s[wid] = sum;
    __syncthreads();

    if (t == 0) {
        float part = s[0] + s[1] + s[2] + s[3];
        __hip_atomic_store(&chbp[b * 8 + kc], part,
                           __ATOMIC_RELEASE, __HIP_MEMORY_SCOPE_AGENT);
        unsigned int old = __hip_atomic_fetch_add(ctr, 1u,
                           __ATOMIC_ACQ_REL, __HIP_MEMORY_SCOPE_AGENT);
        lastflag = (old == RB_GRID - 1) ? 1u : 0u;
    }
    __syncthreads();
    if (!lastflag) return;

    // ---- final combine (single block, fixed order -> deterministic) ----
    float v = 0.f;
    if (t < 128) v = w[t >> 4] * farw[t] * 0.125f;
    if (t < 64)
        v += (CDW * 0.125f / K1) * w[t >> 3] *
             __hip_atomic_load(&chbp[t], __ATOMIC_ACQUIRE, __HIP_MEMORY_SCOPE_AGENT);
#pragma unroll
    for (int off = 32; off; off >>= 1) v += __shfl_down(v, off, 64);
    __syncthreads();                 // protect s[] reuse
    if (lane == 0) s[wid] = v;
    __syncthreads();
    if (t == 0) out[0] = s[0] + s[1] + s[2] + s[3];
}

// ---------------------------------------------------------------------------
extern "C" void kernel_launch(void* const* d_in, const int* in_sizes, int n_in,
                              void* d_out, int out_size, void* d_ws, size_t ws_size,
                              hipStream_t stream) {
    const float* adv = (const float*)d_in[0];
    const float* ori = (const float*)d_in[1];
    const float* w   = (const float*)d_in[2];
    float* ws    = (float*)d_ws;
    float* pmins = ws + PMIN_OFF;
    float* farw  = ws + FARW_OFF;
    float* chbp  = ws + CHB_OFF;
    unsigned int* ctr = (unsigned int*)(ws + CTR_OFF);
    u64*   pk    = (u64*)(ws + PK_OFF);
    float* out   = (float*)d_out;

    prep_far<<<dim3(GRID_P), 256, 0, stream>>>(adv, ori, pk, farw, ctr);
    chamfer_a<<<dim3(CH_GRID), 256, 0, stream>>>(adv, pk, pmins);
    reduce_b<<<dim3(RB_GRID), 256, 0, stream>>>(adv, pmins, farw, w, chbp, ctr, out);
}

// Round 14
// 24.254 us; speedup vs baseline: 1.2733x; 1.2733x over previous
//
#include <hip/hip_runtime.h>
#include <float.h>
#include <math.h>

// Problem constants (fixed by reference)
#define NB    8
#define K1    2048
#define K2    8192
#define NADD  16
#define PP    128          // K1 / NUM_ADD
#define FEPS  1e-7f
#define CDW   0.1f

// Kernel A: 64 farthest blocks + 1024 chamfer blocks = (b, rowblk32, ori-half)
#define FAR_GRID 64
#define CH_GRID  (NB * 64 * 2)        // 1024
#define GRID_A   (FAR_GRID + CH_GRID) // 1088 -> 4.25 blocks/CU

// Kernel B: 64 reduce blocks + last-done combine (proven pattern)
#define RB_GRID  64

// ws layout (float offsets)
#define PMIN_OFF  0                       // [2][NB][K1] = 32768 floats (128 KB)
#define FARW_OFF  32768                   // 128 floats
#define CHB_OFF   (FARW_OFF + NB * NADD)  // 64 floats
#define CTR_OFF   (CHB_OFF + 64)

typedef __bf16 bf16x8 __attribute__((ext_vector_type(8)));
typedef float  f32x16 __attribute__((ext_vector_type(16)));

// ---------------------------------------------------------------------------
// Kernel A: farthest (blocks 0..63, exact fp32) + MFMA chamfer (64..1087).
// Chamfer block = (b, rowblk of 32 adv rows, ori half of 4096 pts):
//   per tile (32 ori pts): load float3 direct from L2, cast-pack to bf16
//   [x,y,z,|o|^2] (x2 replicated), one v_mfma_f32_32x32x16_bf16 against the
//   1/4-scaled replicated A fragment (R13-verified: acc = o^2 - 2 a.o), then
//   16 v_min. No LDS staging at all. 32 tiles/wave, unroll-4 for ILP.
// Epilogue: 5-step col butterfly + cross-wave LDS min -> pmins[half][b][row].
// C layout (m74/m101, R13-verified): col=lane&31, row=(r&3)+8*(r>>2)+4*(lane>>5).
// ---------------------------------------------------------------------------
__global__ __launch_bounds__(256) void fused_a(const float* __restrict__ adv,
                                               const float* __restrict__ ori,
                                               float* __restrict__ pmins,
                                               float* __restrict__ farw,
                                               unsigned int* __restrict__ ctr) {
    __shared__ float sf[768];          // farthest staging
    __shared__ float smin[4][32];
    __shared__ float sred[4];
    const int bid = blockIdx.x;
    const int t   = threadIdx.x;
    if (bid == 0 && t == 0) *ctr = 0u;    // reset kernel-B counter (B runs after A)

    if (bid < FAR_GRID) {
        // ---- farthest: block = (b, cluster-pair), 128 threads per cluster ----
        const int b  = bid >> 3;
        const int cp = bid & 7;
        const int g  = t >> 7;
        const int p  = t & 127;
        const int ci = cp * 2 + g;

        const float* c = adv + (size_t)(b * K1 + ci * PP) * 3;
        float px = c[p * 3 + 0], py = c[p * 3 + 1], pz = c[p * 3 + 2];
        float* sx = sf + g * 384;
        sx[p] = px; sx[128 + p] = py; sx[256 + p] = pz;
        __syncthreads();

        const float pxm = px - FEPS, pym = py - FEPS, pzm = pz - FEPS;
        float mx = 0.f;
#pragma unroll 8
        for (int q = 0; q < PP; ++q) {
            float dx = sx[q] - pxm;
            float dy = sx[128 + q] - pym;
            float dz = sx[256 + q] - pzm;
            mx = fmaxf(mx, fmaf(dx, dx, fmaf(dy, dy, dz * dz)));
        }
#pragma unroll
        for (int off = 32; off; off >>= 1) mx = fmaxf(mx, __shfl_down(mx, off, 64));
        if ((t & 63) == 0) sred[t >> 6] = mx;
        __syncthreads();
        if (t == 0)   farw[b * NADD + cp * 2 + 0] = sqrtf(fmaxf(sred[0], sred[1]));
        if (t == 128) farw[b * NADD + cp * 2 + 1] = sqrtf(fmaxf(sred[2], sred[3]));
    } else {
        // ---- chamfer: block = (b, rowblk, half) ----
        const int cb     = bid - FAR_GRID;
        const int half   = cb & 1;
        const int rowblk = (cb >> 1) & 63;
        const int b      = cb >> 7;
        const int rowb   = rowblk * 32;
        const int lane   = t & 63;
        const int wv     = t >> 6;
        const int col    = lane & 31;

        // A fragment: row = col, quad replicated (j and both halves), 1/4 scale
        const float* a0 = adv + ((size_t)b * K1 + rowb + col) * 3;
        const __bf16 ax = (__bf16)(-0.5f * a0[0]);
        const __bf16 ay = (__bf16)(-0.5f * a0[1]);
        const __bf16 az = (__bf16)(-0.5f * a0[2]);
        const __bf16 aw = (__bf16)0.25f;
        const bf16x8 af = {ax, ay, az, aw, ax, ay, az, aw};

        const f32x16 z16 = {};
        f32x16 m;
#pragma unroll
        for (int r = 0; r < 16; ++r) m[r] = FLT_MAX;

        // this wave: 32 tiles of 32 ori points, direct from L2
        const float* obase = ori + ((size_t)b * K2 + half * 4096 + wv * 1024) * 3;
#pragma unroll 4
        for (int i = 0; i < 32; ++i) {
            const float* op = obase + (size_t)(i * 32 + col) * 3;
            float ox = op[0], oy = op[1], oz = op[2];
            float o2 = fmaf(ox, ox, fmaf(oy, oy, oz * oz));
            const __bf16 bx = (__bf16)ox, by = (__bf16)oy,
                         bz = (__bf16)oz, bw = (__bf16)o2;
            const bf16x8 bf = {bx, by, bz, bw, bx, by, bz, bw};
            f32x16 acc = __builtin_amdgcn_mfma_f32_32x32x16_bf16(af, bf, z16, 0, 0, 0);
#pragma unroll
            for (int r = 0; r < 16; ++r) m[r] = fminf(m[r], acc[r]);
        }

        // min over 32 cols: butterfly on lane&31; rows land per C layout
#pragma unroll
        for (int r = 0; r < 16; ++r) {
            float v = m[r];
#pragma unroll
            for (int msk = 1; msk < 32; msk <<= 1) v = fminf(v, __shfl_xor(v, msk, 64));
            if (col == 0)
                smin[wv][(r & 3) + 8 * (r >> 2) + 4 * (lane >> 5)] = v;
        }
        __syncthreads();

        if (t < 32) {
            float mm = fminf(fminf(smin[0][t], smin[1][t]),
                             fminf(smin[2][t], smin[3][t]));
            pmins[((size_t)half * NB + b) * K1 + rowb + t] = mm;
        }
    }
}

// ---------------------------------------------------------------------------
// Kernel B: min over 2 halves + a^2 + clamp + per-(b,kc) sum; last-done block
// does the final weighted combine (proven R9/R13 pattern, 64 returned RMWs).
// ---------------------------------------------------------------------------
__global__ __launch_bounds__(256) void reduce_b(const float* __restrict__ adv,
                                                const float* __restrict__ pmins,
                                                const float* __restrict__ farw,
                                                const float* __restrict__ w,
                                                float* __restrict__ chbp,
                                                unsigned int* __restrict__ ctr,
                                                float* __restrict__ out) {
    __shared__ float s[4];
    __shared__ unsigned int lastflag;
    const int t  = threadIdx.x;
    const int kc = blockIdx.x & 7;
    const int b  = blockIdx.x >> 3;
    const int k  = kc * 256 + t;

    float m = fminf(pmins[(size_t)b * K1 + k],
                    pmins[((size_t)NB + b) * K1 + k]);
    const float* a = adv + ((size_t)b * K1 + k) * 3;
    float a2 = fmaf(a[0], a[0], fmaf(a[1], a[1], a[2] * a[2]));
    float sum = fmaxf(a2 + m, 0.f);          // clamp commutes with min

#pragma unroll
    for (int off = 32; off; off >>= 1) sum += __shfl_down(sum, off, 64);
    const int lane = t & 63, wid = t >> 6;
    if (lane == 0) s[wid] = sum;
    __syncthreads();

    if (t == 0) {
        float part = s[0] + s[1] + s[2] + s[3];
        __hip_atomic_store(&chbp[b * 8 + kc], part,
                           __ATOMIC_RELEASE, __HIP_MEMORY_SCOPE_AGENT);
        unsigned int old = __hip_atomic_fetch_add(ctr, 1u,
                           __ATOMIC_ACQ_REL, __HIP_MEMORY_SCOPE_AGENT);
        lastflag = (old == RB_GRID - 1) ? 1u : 0u;
    }
    __syncthreads();
    if (!lastflag) return;

    // ---- final combine (single block, fixed order -> deterministic) ----
    float v = 0.f;
    if (t < 128) v = w[t >> 4] * farw[t] * 0.125f;
    if (t < 64)
        v += (CDW * 0.125f / K1) * w[t >> 3] *
             __hip_atomic_load(&chbp[t], __ATOMIC_ACQUIRE, __HIP_MEMORY_SCOPE_AGENT);
#pragma unroll
    for (int off = 32; off; off >>= 1) v += __shfl_down(v, off, 64);
    __syncthreads();                 // protect s[] reuse
    if (lane == 0) s[wid] = v;
    __syncthreads();
    if (t == 0) out[0] = s[0] + s[1] + s[2] + s[3];
}

// ---------------------------------------------------------------------------
extern "C" void kernel_launch(void* const* d_in, const int* in_sizes, int n_in,
                              void* d_out, int out_size, void* d_ws, size_t ws_size,
                              hipStream_t stream) {
    const float* adv = (const float*)d_in[0];
    const float* ori = (const float*)d_in[1];
    const float* w   = (const float*)d_in[2];
    float* ws    = (float*)d_ws;
    float* pmins = ws + PMIN_OFF;
    float* farw  = ws + FARW_OFF;
    float* chbp  = ws + CHB_OFF;
    unsigned int* ctr = (unsigned int*)(ws + CTR_OFF);
    float* out   = (float*)d_out;

    fused_a<<<dim3(GRID_A), 256, 0, stream>>>(adv, ori, pmins, farw, ctr);
    reduce_b<<<dim3(RB_GRID), 256, 0, stream>>>(adv, pmins, farw, w, chbp, ctr, out);
}